// Round 4
// baseline (507.657 us; speedup 1.0000x reference)
//
#include <hip/hip_runtime.h>

#define ROWS 16384
#define COLS 4096
#define KSEL 512
#define THREADS 256
#define NCOPY0 8       // pass-0 histogram copies (hot bins from normal data)
#define HSTRIDE 260    // words per copy: bank-skewed (260%32==4), 16B-aligned
#define NBLOCKS 2048   // 8 persistent blocks per CU
#define ROWS_PER_BLOCK (ROWS / NBLOCKS)  // 8
// LDS: (NCOPY0 + 3) * HSTRIDE * 4 = 11440 B -> 8 blocks/CU = 91.5 KB of 160 KB

// order-preserving float->uint map: compare as unsigned == compare as float
__device__ __forceinline__ unsigned map_f(float f) {
    unsigned u = __float_as_uint(f);
    return u ^ (0x80000000u | (unsigned)((int)u >> 31));
}
__device__ __forceinline__ float unmap_f(unsigned m) {
    return __uint_as_float(m ^ (0x80000000u | ~(unsigned)((int)m >> 31)));
}

// wave-redundant digit select: lane owns bins [4*lane .. 4*lane+3] with counts
// n0..n3; suffix-scan across the wave locates the digit containing rank kk.
__device__ __forceinline__ void select_digit(unsigned n0, unsigned n1, unsigned n2,
                                             unsigned n3, int lane, int shift,
                                             unsigned& prefix, unsigned& kk) {
    unsigned ls3 = n3, ls2 = n3 + n2, ls1 = ls2 + n1, tot = ls1 + n0;
    unsigned S = tot;
#pragma unroll
    for (int off = 1; off < 64; off <<= 1) {
        unsigned o = __shfl(S, lane + off);
        S += (lane + off < 64) ? o : 0u;
    }
    const unsigned R = S - tot;  // count with digit >= 4*(lane+1)
    const unsigned S3 = R + ls3, S2 = R + ls2, S1 = R + ls1, S0 = R + tot;
    unsigned dig = 0, nk = 0;
    bool found = false;
    if (S3 >= kk && R  < kk) { dig = 4 * lane + 3; nk = kk - R;  found = true; }
    if (S2 >= kk && S3 < kk) { dig = 4 * lane + 2; nk = kk - S3; found = true; }
    if (S1 >= kk && S2 < kk) { dig = 4 * lane + 1; nk = kk - S2; found = true; }
    if (S0 >= kk && S1 < kk) { dig = 4 * lane + 0; nk = kk - S1; found = true; }
    unsigned long long m = __ballot(found);
    int src = (int)__ffsll(m) - 1;
    prefix |= (unsigned)__shfl(dig, src) << shift;
    kk = (unsigned)__shfl(nk, src);
}

__global__ __launch_bounds__(THREADS, 8) void kwta_kernel(const float* __restrict__ in,
                                                          float* __restrict__ out) {
    __shared__ __align__(16) unsigned hist[(NCOPY0 + 3) * HSTRIDE];

    const int tid  = threadIdx.x;
    const int lane = tid & 63;
    const int bid  = blockIdx.x;

    // prefetch row 0 for this block
    float4 fnext[4];
    {
        const float4* __restrict__ p = (const float4*)(in + (size_t)bid * COLS);
#pragma unroll
        for (int i = 0; i < 4; i++) fnext[i] = p[tid + THREADS * i];
    }

#pragma unroll 1
    for (int j = 0; j < ROWS_PER_BLOCK; j++) {
        const size_t row = (size_t)j * NBLOCKS + bid;

        // consume prefetched row into mapped space
        unsigned v[16];
#pragma unroll
        for (int i = 0; i < 4; i++) {
            v[4 * i + 0] = map_f(fnext[i].x);
            v[4 * i + 1] = map_f(fnext[i].y);
            v[4 * i + 2] = map_f(fnext[i].z);
            v[4 * i + 3] = map_f(fnext[i].w);
        }

        // issue next row's loads NOW — they fly under the whole select phase
        if (j + 1 < ROWS_PER_BLOCK) {
            const float4* __restrict__ p =
                (const float4*)(in + ((size_t)(j + 1) * NBLOCKS + bid) * COLS);
#pragma unroll
            for (int i = 0; i < 4; i++) fnext[i] = p[tid + THREADS * i];
        }

        // ensure prior row's scan reads are done before re-zeroing
        __syncthreads();
        {
            const uint4 z = make_uint4(0u, 0u, 0u, 0u);
#pragma unroll
            for (int i = 0; i < 3; i++) {
                int w4 = tid + THREADS * i;
                if (w4 < (NCOPY0 + 3) * HSTRIDE / 4) ((uint4*)hist)[w4] = z;
            }
        }
        __syncthreads();

        unsigned prefix = 0;
        unsigned kk = KSEL;

        // ---- pass 0: top byte, 8-copy histogram (contention-spread) ----
        {
            unsigned* h0 = hist + (tid & (NCOPY0 - 1)) * HSTRIDE;
#pragma unroll
            for (int i = 0; i < 16; i++) atomicAdd(&h0[v[i] >> 24], 1u);
            __syncthreads();
            unsigned n0 = 0, n1 = 0, n2 = 0, n3 = 0;
#pragma unroll
            for (int c = 0; c < NCOPY0; c++) {
                uint4 t = ((const uint4*)(hist + c * HSTRIDE))[lane];
                n0 += t.x; n1 += t.y; n2 += t.z; n3 += t.w;
            }
            select_digit(n0, n1, n2, n3, lane, 24, prefix, kk);
        }

        // ---- passes 1..3: private single-copy buffers (near-uniform digits);
        // disjoint LDS regions -> pass p atomics never race pass p-1 reads
#pragma unroll
        for (int pass = 1; pass < 4; pass++) {
            const int shift = 24 - 8 * pass;
            const int hs = shift + 8;
            unsigned* hp = hist + (NCOPY0 + pass - 1) * HSTRIDE;
#pragma unroll
            for (int i = 0; i < 16; i++) {
                if (((v[i] ^ prefix) >> hs) == 0u)
                    atomicAdd(&hp[(v[i] >> shift) & 255u], 1u);
            }
            __syncthreads();
            uint4 t = ((const uint4*)hp)[lane];
            select_digit(t.x, t.y, t.z, t.w, lane, shift, prefix, kk);
        }

        // prefix == mapped bits of the exact K-th largest; compare in mapped space
        float4* __restrict__ outrow = (float4*)(out + row * COLS);
#pragma unroll
        for (int i = 0; i < 4; i++) {
            float4 o;
            o.x = (v[4 * i + 0] >= prefix) ? unmap_f(v[4 * i + 0]) : 0.0f;
            o.y = (v[4 * i + 1] >= prefix) ? unmap_f(v[4 * i + 1]) : 0.0f;
            o.z = (v[4 * i + 2] >= prefix) ? unmap_f(v[4 * i + 2]) : 0.0f;
            o.w = (v[4 * i + 3] >= prefix) ? unmap_f(v[4 * i + 3]) : 0.0f;
            outrow[tid + THREADS * i] = o;
        }
    }
}

extern "C" void kernel_launch(void* const* d_in, const int* in_sizes, int n_in,
                              void* d_out, int out_size, void* d_ws, size_t ws_size,
                              hipStream_t stream) {
    const float* s = (const float*)d_in[0];
    float* out = (float*)d_out;
    kwta_kernel<<<NBLOCKS, THREADS, 0, stream>>>(s, out);
}